// Round 6
// baseline (456.115 us; speedup 1.0000x reference)
//
#include <hip/hip_runtime.h>
#include <hip/hip_bf16.h>
#include <stdint.h>

#define AS_GLOBAL __attribute__((address_space(1)))
#define AS_LDS    __attribute__((address_space(3)))

typedef __attribute__((ext_vector_type(8))) short  bf16x8;
typedef __attribute__((ext_vector_type(4))) float  f32x4;
typedef __attribute__((ext_vector_type(8))) short  s16x8;

__device__ __forceinline__ void gload_lds16(const void* g, void* l) {
    __builtin_amdgcn_global_load_lds((AS_GLOBAL const void*)g, (AS_LDS void*)l, 16, 0, 0);
}

// Cast 8 fp32 -> 8 bf16 (one 16B store), pair index p into region (s,d).
__device__ __forceinline__ void cast_pair(const float* __restrict__ s,
                                          __hip_bfloat16* __restrict__ d, long p) {
    f32x4 a = ((const f32x4*)s)[p * 2];
    f32x4 b = ((const f32x4*)s)[p * 2 + 1];
    union { s16x8 p8; __hip_bfloat16 h[8]; } u;
    u.h[0] = __float2bfloat16(a.x); u.h[1] = __float2bfloat16(a.y);
    u.h[2] = __float2bfloat16(a.z); u.h[3] = __float2bfloat16(a.w);
    u.h[4] = __float2bfloat16(b.x); u.h[5] = __float2bfloat16(b.y);
    u.h[6] = __float2bfloat16(b.z); u.h[7] = __float2bfloat16(b.w);
    ((s16x8*)d)[p] = u.p8;
}

// castA: x (262144 pairs) + W1 (1048576 pairs); 1280 blocks x 256 x 4 iters. [R0]
__global__ void cast_a_k(const float* __restrict__ x,  __hip_bfloat16* __restrict__ xb,
                         const float* __restrict__ W1, __hip_bfloat16* __restrict__ W1b) {
    const long nx = 262144, ntot = 1310720, stride = 1280 * 256;
    long t = (long)blockIdx.x * 256 + threadIdx.x;
    for (long p = t; p < ntot; p += stride) {
        if (p < nx) cast_pair(x, xb, p);
        else        cast_pair(W1, W1b, p - nx);
    }
}

// ---------------------------------------------------------------------------
// R0-exact 128x128 split-K GEMM (used for layers 1 and 3). launch_bounds(256,3).
// FUSECAST leading z-planes cast W2/W3 (overlaps GEMM1). Verified 250.6us config.
// ---------------------------------------------------------------------------
template <int FUSECAST>
__global__ __launch_bounds__(256, 3)
void gemm_btk(const __hip_bfloat16* __restrict__ A,
              const __hip_bfloat16* __restrict__ Bm,
              __hip_bfloat16* __restrict__ P,
              const int M, const int N, const int kchunk, const int S,
              const float* __restrict__ cs1, __hip_bfloat16* __restrict__ cd1, const long cn1,
              const float* __restrict__ cs2, __hip_bfloat16* __restrict__ cd2, const long cn2)
{
    __shared__ __hip_bfloat16 As[128 * 64];
    __shared__ __hip_bfloat16 Bs[128 * 64];

    const int tid = threadIdx.x;
    const int bn = blockIdx.x, bm = blockIdx.y, z = blockIdx.z;

    if (FUSECAST && z < FUSECAST) {
        const long nb     = (long)gridDim.x * gridDim.y;
        const long stride = FUSECAST * nb * 256;
        long t = ((long)z * nb + (long)bm * gridDim.x + bn) * 256 + tid;
        const long ntot = cn1 + cn2;
        for (long p = t; p < ntot; p += stride) {
            if (p < cn1) cast_pair(cs1, cd1, p);
            else         cast_pair(cs2, cd2, p - cn1);
        }
        return;
    }
    const int kz = z - FUSECAST;

    const int lane = tid & 63;
    const int wave = tid >> 6;
    const int wm   = wave >> 1, wn = wave & 1;
    const int lm   = lane & 15, lq = lane >> 4;

    const int K  = kchunk * S;
    const int k0 = kz * kchunk;

    const int rlo  = lane >> 3;
    const int gsw8 = (((lane & 7) ^ rlo) << 3);

    const __hip_bfloat16* Ag = A  + (size_t)(bm * 128) * K;
    const __hip_bfloat16* Bg = Bm + (size_t)(bn * 128) * K;

    f32x4 acc[4][4];
    #pragma unroll
    for (int i = 0; i < 4; ++i)
        #pragma unroll
        for (int j = 0; j < 4; ++j)
            acc[i][j] = (f32x4){0.f, 0.f, 0.f, 0.f};

    for (int kt = k0; kt < k0 + kchunk; kt += 64) {
        __syncthreads();
        #pragma unroll
        for (int c = 0; c < 4; ++c) {
            const int chunk = wave * 4 + c;
            const int row   = chunk * 8 + rlo;
            gload_lds16(Ag + (size_t)row * K + kt + gsw8, As + chunk * 512);
            gload_lds16(Bg + (size_t)row * K + kt + gsw8, Bs + chunk * 512);
        }
        __syncthreads();
        #pragma unroll
        for (int kk = 0; kk < 2; ++kk) {
            const int sl = (((kk * 4 + lq) ^ (lm & 7)) << 3);
            bf16x8 af[4], bq[4];
            #pragma unroll
            for (int i = 0; i < 4; ++i)
                af[i] = *(const bf16x8*)(As + (wm * 64 + i * 16 + lm) * 64 + sl);
            #pragma unroll
            for (int j = 0; j < 4; ++j)
                bq[j] = *(const bf16x8*)(Bs + (wn * 64 + j * 16 + lm) * 64 + sl);
            #pragma unroll
            for (int i = 0; i < 4; ++i)
                #pragma unroll
                for (int j = 0; j < 4; ++j)
                    acc[i][j] = __builtin_amdgcn_mfma_f32_16x16x32_bf16(af[i], bq[j], acc[i][j], 0, 0, 0);
        }
    }

    __hip_bfloat16* Pz = P + (size_t)kz * M * N;
    const int row0 = bm * 128 + wm * 64;
    const int colb = bn * 128 + wn * 64 + lm;
    #pragma unroll
    for (int j = 0; j < 4; ++j) {
        const int col = colb + j * 16;
        #pragma unroll
        for (int i = 0; i < 4; ++i)
            #pragma unroll
            for (int r = 0; r < 4; ++r) {
                const int row = row0 + i * 16 + lq * 4 + r;
                Pz[(size_t)row * N + col] = __float2bfloat16(acc[i][j][r]);
            }
    }
}

// ---------------------------------------------------------------------------
// NEW (R6): 256x256-tile, BK=64, 8-wave, double-buffered pipelined GEMM for
// layer 2 (the largest GEMM). Rationale: R0-R5 established throughput here is
// proportional to bytes staged into LDS (≈9.7 TB/s aggregate at the 2-barrier
// 128^2 structure; dbuf/TLP neutral). 256^2 halves staged bytes per FLOP, and
// the 4-phase-per-tile interleave (stage-next || ds_read || 16-MFMA clusters
// || s_barrier), with the vmcnt drain only at tile boundaries, gives every
// staged load >=2 phases of in-flight slack (T3+T4 minimum; guide Sec 5).
// Hazards: staging always writes the non-read buffer; boundary __syncthreads
// (vmcnt(0)+lgkmcnt(0)+barrier) protects buffer handoff. No intra-tile hazard.
// Swizzle: identical verified formula (granule g of row r at slot g^(r&7)).
// acc indexing fully compile-time (phases instantiated as macros, rule #20).
// ---------------------------------------------------------------------------
__global__ __launch_bounds__(512, 2)
void gemm8p(const __hip_bfloat16* __restrict__ A,
            const __hip_bfloat16* __restrict__ Bm,
            __hip_bfloat16* __restrict__ P,
            const int M, const int N, const int kchunk, const int S)
{
    __shared__ __hip_bfloat16 As[2][256 * 64];   // 2 x 32 KB
    __shared__ __hip_bfloat16 Bs[2][256 * 64];   // 2 x 32 KB  (total 128 KB)

    const int tid  = threadIdx.x;
    const int bn   = blockIdx.x, bm = blockIdx.y, kz = blockIdx.z;
    const int lane = tid & 63;
    const int wave = tid >> 6;          // 0..7
    const int wm   = wave >> 2;         // 0..1  (M half: 128 rows)
    const int wn   = wave & 3;          // 0..3  (N quarter: 64 cols)
    const int lm   = lane & 15, lq = lane >> 4;

    const int K  = kchunk * S;
    const int k0 = kz * kchunk;
    const int nt = kchunk >> 6;         // K-tiles of 64

    const int rlo  = lane >> 3;
    const int gsw8 = (((lane & 7) ^ rlo) << 3);

    const __hip_bfloat16* Ag = A  + (size_t)(bm * 256) * K;
    const __hip_bfloat16* Bg = Bm + (size_t)(bn * 256) * K;

    f32x4 acc[8][4];
    #pragma unroll
    for (int i = 0; i < 8; ++i)
        #pragma unroll
        for (int j = 0; j < 4; ++j)
            acc[i][j] = (f32x4){0.f, 0.f, 0.f, 0.f};

    // Wave stages chunks 4w..4w+3 of each operand (32 chunks = 256 rows each).
    auto stageA = [&](int d, int kt) {
        #pragma unroll
        for (int c = 0; c < 4; ++c) {
            const int chunk = wave * 4 + c;          // 0..31
            const int row   = chunk * 8 + rlo;       // 0..255
            gload_lds16(Ag + (size_t)row * K + kt + gsw8, &As[d][chunk * 512]);
        }
    };
    auto stageB = [&](int d, int kt) {
        #pragma unroll
        for (int c = 0; c < 4; ++c) {
            const int chunk = wave * 4 + c;
            const int row   = chunk * 8 + rlo;
            gload_lds16(Bg + (size_t)row * K + kt + gsw8, &Bs[d][chunk * 512]);
        }
    };

    // One phase: 8 ds_read_b128 + 16 MFMA, all indices compile-time.
#define PHASE(KK_, IH_, D_)                                                        \
    {                                                                              \
        const int sl = ((((KK_) * 4 + lq) ^ (lm & 7)) << 3);                       \
        bf16x8 af[4], bq[4];                                                       \
        _Pragma("unroll")                                                          \
        for (int i2 = 0; i2 < 4; ++i2)                                             \
            af[i2] = *(const bf16x8*)(&As[D_][(wm * 128 + ((IH_) * 4 + i2) * 16 + lm) * 64 + sl]); \
        _Pragma("unroll")                                                          \
        for (int j = 0; j < 4; ++j)                                                \
            bq[j] = *(const bf16x8*)(&Bs[D_][(wn * 64 + j * 16 + lm) * 64 + sl]);  \
        __builtin_amdgcn_s_setprio(1);                                             \
        _Pragma("unroll")                                                          \
        for (int i2 = 0; i2 < 4; ++i2)                                             \
            _Pragma("unroll")                                                      \
            for (int j = 0; j < 4; ++j)                                            \
                acc[(IH_) * 4 + i2][j] =                                           \
                    __builtin_amdgcn_mfma_f32_16x16x32_bf16(af[i2], bq[j],         \
                                                            acc[(IH_) * 4 + i2][j], 0, 0, 0); \
        __builtin_amdgcn_s_setprio(0);                                             \
    }

    // Prologue: stage tile 0, full drain.
    stageA(0, k0);
    stageB(0, k0);
    __syncthreads();

    int cur = 0;
    for (int t = 0; t < nt; ++t) {
        const int ktn  = k0 + (t + 1) * 64;
        const bool pre = (t + 1 < nt);
        if (cur == 0) {
            if (pre) stageA(1, ktn);           // phase 0: prefetch A(t+1)
            PHASE(0, 0, 0)
            __builtin_amdgcn_s_barrier();
            if (pre) stageB(1, ktn);           // phase 1: prefetch B(t+1)
            PHASE(0, 1, 0)
            __builtin_amdgcn_s_barrier();
            PHASE(1, 0, 0)                     // phase 2
            __builtin_amdgcn_s_barrier();
            PHASE(1, 1, 0)                     // phase 3
        } else {
            if (pre) stageA(0, ktn);
            PHASE(0, 0, 1)
            __builtin_amdgcn_s_barrier();
            if (pre) stageB(0, ktn);
            PHASE(0, 1, 1)
            __builtin_amdgcn_s_barrier();
            PHASE(1, 0, 1)
            __builtin_amdgcn_s_barrier();
            PHASE(1, 1, 1)
        }
        __syncthreads();   // tile boundary: drains vmcnt (t+1 buffer complete)
        cur ^= 1;
    }
#undef PHASE

    __hip_bfloat16* Pz = P + (size_t)kz * M * N;
    const int row0 = bm * 256 + wm * 128;
    const int colb = bn * 256 + wn * 64 + lm;
    #pragma unroll
    for (int j = 0; j < 4; ++j) {
        const int col = colb + j * 16;
        #pragma unroll
        for (int i = 0; i < 8; ++i)
            #pragma unroll
            for (int r = 0; r < 4; ++r) {
                const int row = row0 + i * 16 + lq * 4 + r;
                Pz[(size_t)row * N + col] = __float2bfloat16(acc[i][j][r]);
            }
    }
}

// T-collapse: za = sum_{u=1..T} w_u * relu(c_u*y + b2).
template <int TT>
__device__ __forceinline__ void tcollapse_coef(float be1, float be2, float be3,
                                               float* __restrict__ c, float* __restrict__ w) {
    float g[TT + 1];
    g[TT] = 1.f;
    float p3 = 1.f;
    #pragma unroll
    for (int u = TT - 1; u >= 1; --u) {
        p3 *= be3;
        g[u] = be2 * g[u + 1] + p3;
    }
    const float s = (1.f - be2) * (1.f - be3);
    float p1 = 1.f;
    #pragma unroll
    for (int u = 1; u <= TT; ++u) {
        p1 *= be1;
        c[u - 1] = 1.f - p1;
        w[u - 1] = s * g[u];
    }
}

// Sum S bf16 split-K partials + epilogue. 8 elems/thread. [R0]
template <int MODE>
__global__ void reduce_k(const __hip_bfloat16* __restrict__ P, const int S,
                         void* __restrict__ outv, const long MN, const int N,
                         const float* __restrict__ bias,
                         const float* __restrict__ b_taus,
                         const int* __restrict__ Tp)
{
    long i8 = (long)blockIdx.x * 256 + threadIdx.x;
    long i  = i8 * 8;
    float a[8] = {0.f, 0.f, 0.f, 0.f, 0.f, 0.f, 0.f, 0.f};
    for (int s = 0; s < S; ++s) {
        union { s16x8 p8; __hip_bfloat16 h[8]; } u;
        u.p8 = *(const s16x8*)(P + (size_t)s * MN + i);
        #pragma unroll
        for (int c = 0; c < 8; ++c) a[c] += __bfloat162float(u.h[c]);
    }
    const int col = (int)(i % N);
    float bb[8];
    #pragma unroll
    for (int c = 0; c < 8; ++c) bb[c] = bias[col + c];

    if constexpr (MODE == 0) {
        union { s16x8 p8; __hip_bfloat16 h[8]; } u;
        #pragma unroll
        for (int c = 0; c < 8; ++c)
            u.h[c] = __float2bfloat16(fmaxf(a[c] + bb[c], 0.f));
        ((s16x8*)outv)[i8] = u.p8;
    } else if constexpr (MODE == 1) {
        const int   T   = *Tp;
        const float be1 = 1.f / (1.f + expf(-b_taus[0]));
        const float be2 = 1.f / (1.f + expf(-b_taus[1]));
        const float be3 = 1.f / (1.f + expf(-b_taus[2]));
        union { s16x8 p8; __hip_bfloat16 h[8]; } u;
        if (T == 10) {
            float c10[10], w10[10];
            tcollapse_coef<10>(be1, be2, be3, c10, w10);
            #pragma unroll
            for (int c = 0; c < 8; ++c) {
                float za = 0.f;
                #pragma unroll
                for (int t = 0; t < 10; ++t)
                    za += w10[t] * fmaxf(fmaf(c10[t], a[c], bb[c]), 0.f);
                u.h[c] = __float2bfloat16(za);
            }
        } else {
            #pragma unroll
            for (int c = 0; c < 8; ++c) {
                float p1 = 1.f, s2 = 0.f, za = 0.f;
                for (int t = 0; t < T; ++t) {
                    p1 *= be1;
                    const float d2 = fmaxf(fmaf(1.f - p1, a[c], bb[c]), 0.f);
                    s2 = be2 * s2 + (1.f - be2) * d2;
                    za = be3 * za + (1.f - be3) * s2;
                }
                u.h[c] = __float2bfloat16(za);
            }
        }
        ((s16x8*)outv)[i8] = u.p8;
    } else {
        const int   T   = *Tp;
        const float be3 = 1.f / (1.f + expf(-b_taus[2]));
        float g = 0.f;
        for (int t = 0; t < T; ++t) g = be3 * g + (1.f - be3);
        f32x4 o0, o1;
        o0.x = a[0] + g * bb[0]; o0.y = a[1] + g * bb[1];
        o0.z = a[2] + g * bb[2]; o0.w = a[3] + g * bb[3];
        o1.x = a[4] + g * bb[4]; o1.y = a[5] + g * bb[5];
        o1.z = a[6] + g * bb[6]; o1.w = a[7] + g * bb[7];
        ((f32x4*)outv)[i8 * 2]     = o0;
        ((f32x4*)outv)[i8 * 2 + 1] = o1;
    }
}

extern "C" void kernel_launch(void* const* d_in, const int* in_sizes, int n_in,
                              void* d_out, int out_size, void* d_ws, size_t ws_size,
                              hipStream_t stream) {
    const float* x      = (const float*)d_in[0];
    const float* W1     = (const float*)d_in[1];
    const float* b1     = (const float*)d_in[2];
    const float* W2     = (const float*)d_in[3];
    const float* b2     = (const float*)d_in[4];
    const float* W3     = (const float*)d_in[5];
    const float* b3     = (const float*)d_in[6];
    const float* b_taus = (const float*)d_in[7];
    const int*   Tp     = (const int*)d_in[8];

    const int B = 1024, DIN = 2048, H1 = 4096, H2 = 4096, DOUT = 1024;
    const long MB = 1024 * 1024;

    // Arena (108 MB): xb 0 (4MB), W1b 4 (16MB), W2b 20 (32MB), W3b 52 (8MB),
    // D1b 60 (8MB), Sb 68 (8MB), Pb 76 (32MB shared by all split-K phases).
    char* ws = (char*)d_ws;
    __hip_bfloat16* xb  = (__hip_bfloat16*)(ws + 0);
    __hip_bfloat16* W1b = (__hip_bfloat16*)(ws + 4 * MB);
    __hip_bfloat16* W2b = (__hip_bfloat16*)(ws + 20 * MB);
    __hip_bfloat16* W3b = (__hip_bfloat16*)(ws + 52 * MB);
    __hip_bfloat16* D1b = (__hip_bfloat16*)(ws + 60 * MB);
    __hip_bfloat16* Sb  = (__hip_bfloat16*)(ws + 68 * MB);
    __hip_bfloat16* Pb  = (__hip_bfloat16*)(ws + 76 * MB);

    // castA: x + W1 (gates gemm1) [R0]
    cast_a_k<<<dim3(1280), dim3(256), 0, stream>>>(x, xb, W1, W1b);

    // Layer 1: R0-exact 128^2 GEMM, S=2, +1 cast plane (W2/W3).
    gemm_btk<1><<<dim3(H1 / 128, B / 128, 1 + 2), 256, 0, stream>>>(
        xb, W1b, Pb, B, H1, DIN / 2, 2,
        W2, W2b, (long)H2 * H1 / 8, W3, W3b, (long)DOUT * H2 / 8);
    reduce_k<0><<<dim3(2048), 256, 0, stream>>>(Pb, 2, (void*)D1b, (long)B * H1, H1, b1, nullptr, nullptr);

    // Layer 2: NEW 256^2 8-phase pipelined GEMM. S=4 -> 256 blocks (1/CU),
    // kchunk=1024 -> 16 K-tiles.
    gemm8p<<<dim3(H2 / 256, B / 256, 4), 512, 0, stream>>>(
        D1b, W2b, Pb, B, H2, H1 / 4, 4);
    reduce_k<1><<<dim3(2048), 256, 0, stream>>>(Pb, 4, (void*)Sb, (long)B * H2, H2, b2, b_taus, Tp);

    // Layer 3: R0-exact 128^2 GEMM, S=8.
    gemm_btk<0><<<dim3(DOUT / 128, B / 128, 8), 256, 0, stream>>>(
        Sb, W3b, Pb, B, DOUT, H2 / 8, 8, nullptr, nullptr, 0, nullptr, nullptr, 0);
    reduce_k<2><<<dim3(512), 256, 0, stream>>>(Pb, 8, d_out, (long)B * DOUT, DOUT, b3, b_taus, Tp);
}

// Round 8
// 455.594 us; speedup vs baseline: 1.0011x; 1.0011x over previous
//
#include <hip/hip_runtime.h>
#include <hip/hip_bf16.h>
#include <stdint.h>

#define AS_GLOBAL __attribute__((address_space(1)))
#define AS_LDS    __attribute__((address_space(3)))

typedef __attribute__((ext_vector_type(8))) short  bf16x8;
typedef __attribute__((ext_vector_type(4))) float  f32x4;
typedef __attribute__((ext_vector_type(8))) short  s16x8;

__device__ __forceinline__ void gload_lds16(const void* g, void* l) {
    __builtin_amdgcn_global_load_lds((AS_GLOBAL const void*)g, (AS_LDS void*)l, 16, 0, 0);
}

// Cast 8 fp32 -> 8 bf16 (one 16B store), pair index p into region (s,d).
__device__ __forceinline__ void cast_pair(const float* __restrict__ s,
                                          __hip_bfloat16* __restrict__ d, long p) {
    f32x4 a = ((const f32x4*)s)[p * 2];
    f32x4 b = ((const f32x4*)s)[p * 2 + 1];
    union { s16x8 p8; __hip_bfloat16 h[8]; } u;
    u.h[0] = __float2bfloat16(a.x); u.h[1] = __float2bfloat16(a.y);
    u.h[2] = __float2bfloat16(a.z); u.h[3] = __float2bfloat16(a.w);
    u.h[4] = __float2bfloat16(b.x); u.h[5] = __float2bfloat16(b.y);
    u.h[6] = __float2bfloat16(b.z); u.h[7] = __float2bfloat16(b.w);
    ((s16x8*)d)[p] = u.p8;
}

// castA: x (262144 pairs) + W1 (1048576 pairs); 1280 blocks x 256 x 4 iters. [R0]
__global__ void cast_a_k(const float* __restrict__ x,  __hip_bfloat16* __restrict__ xb,
                         const float* __restrict__ W1, __hip_bfloat16* __restrict__ W1b) {
    const long nx = 262144, ntot = 1310720, stride = 1280 * 256;
    long t = (long)blockIdx.x * 256 + threadIdx.x;
    for (long p = t; p < ntot; p += stride) {
        if (p < nx) cast_pair(x, xb, p);
        else        cast_pair(W1, W1b, p - nx);
    }
}

// ---------------------------------------------------------------------------
// R0-exact 128x128 split-K GEMM (layers 1 and 3). launch_bounds(256,3).
// FUSECAST leading z-planes cast W2/W3 (overlaps GEMM1). Verified 250.6us config.
// ---------------------------------------------------------------------------
template <int FUSECAST>
__global__ __launch_bounds__(256, 3)
void gemm_btk(const __hip_bfloat16* __restrict__ A,
              const __hip_bfloat16* __restrict__ Bm,
              __hip_bfloat16* __restrict__ P,
              const int M, const int N, const int kchunk, const int S,
              const float* __restrict__ cs1, __hip_bfloat16* __restrict__ cd1, const long cn1,
              const float* __restrict__ cs2, __hip_bfloat16* __restrict__ cd2, const long cn2)
{
    __shared__ __hip_bfloat16 As[128 * 64];
    __shared__ __hip_bfloat16 Bs[128 * 64];

    const int tid = threadIdx.x;
    const int bn = blockIdx.x, bm = blockIdx.y, z = blockIdx.z;

    if (FUSECAST && z < FUSECAST) {
        const long nb     = (long)gridDim.x * gridDim.y;
        const long stride = FUSECAST * nb * 256;
        long t = ((long)z * nb + (long)bm * gridDim.x + bn) * 256 + tid;
        const long ntot = cn1 + cn2;
        for (long p = t; p < ntot; p += stride) {
            if (p < cn1) cast_pair(cs1, cd1, p);
            else         cast_pair(cs2, cd2, p - cn1);
        }
        return;
    }
    const int kz = z - FUSECAST;

    const int lane = tid & 63;
    const int wave = tid >> 6;
    const int wm   = wave >> 1, wn = wave & 1;
    const int lm   = lane & 15, lq = lane >> 4;

    const int K  = kchunk * S;
    const int k0 = kz * kchunk;

    const int rlo  = lane >> 3;
    const int gsw8 = (((lane & 7) ^ rlo) << 3);

    const __hip_bfloat16* Ag = A  + (size_t)(bm * 128) * K;
    const __hip_bfloat16* Bg = Bm + (size_t)(bn * 128) * K;

    f32x4 acc[4][4];
    #pragma unroll
    for (int i = 0; i < 4; ++i)
        #pragma unroll
        for (int j = 0; j < 4; ++j)
            acc[i][j] = (f32x4){0.f, 0.f, 0.f, 0.f};

    for (int kt = k0; kt < k0 + kchunk; kt += 64) {
        __syncthreads();
        #pragma unroll
        for (int c = 0; c < 4; ++c) {
            const int chunk = wave * 4 + c;
            const int row   = chunk * 8 + rlo;
            gload_lds16(Ag + (size_t)row * K + kt + gsw8, As + chunk * 512);
            gload_lds16(Bg + (size_t)row * K + kt + gsw8, Bs + chunk * 512);
        }
        __syncthreads();
        #pragma unroll
        for (int kk = 0; kk < 2; ++kk) {
            const int sl = (((kk * 4 + lq) ^ (lm & 7)) << 3);
            bf16x8 af[4], bq[4];
            #pragma unroll
            for (int i = 0; i < 4; ++i)
                af[i] = *(const bf16x8*)(As + (wm * 64 + i * 16 + lm) * 64 + sl);
            #pragma unroll
            for (int j = 0; j < 4; ++j)
                bq[j] = *(const bf16x8*)(Bs + (wn * 64 + j * 16 + lm) * 64 + sl);
            #pragma unroll
            for (int i = 0; i < 4; ++i)
                #pragma unroll
                for (int j = 0; j < 4; ++j)
                    acc[i][j] = __builtin_amdgcn_mfma_f32_16x16x32_bf16(af[i], bq[j], acc[i][j], 0, 0, 0);
        }
    }

    __hip_bfloat16* Pz = P + (size_t)kz * M * N;
    const int row0 = bm * 128 + wm * 64;
    const int colb = bn * 128 + wn * 64 + lm;
    #pragma unroll
    for (int j = 0; j < 4; ++j) {
        const int col = colb + j * 16;
        #pragma unroll
        for (int i = 0; i < 4; ++i)
            #pragma unroll
            for (int r = 0; r < 4; ++r) {
                const int row = row0 + i * 16 + lq * 4 + r;
                Pz[(size_t)row * N + col] = __float2bfloat16(acc[i][j][r]);
            }
    }
}

// ---------------------------------------------------------------------------
// 256x256-tile, BK=64, 8-wave, double-buffered pipelined GEMM (layer 2).
// R7 fix vs R6: __launch_bounds__(512, 1). R6's (512,2) = 4 waves/SIMD capped
// the allocator at 128 VGPR/thread -- exactly the acc[8][4] footprint -- so
// everything else spilled (WRITE_SIZE 662MB of scratch, 250us). 128KB LDS
// already limits residency to 1 block/CU, so (512,1) gives the 256-VGPR
// budget for free (m201 template profile: 8 waves, 128KB, ~250 VGPR).
// Per-tile: 4 phases {stage-next || 8x ds_read_b128 || 16 MFMA (setprio) ||
// s_barrier}; vmcnt drain only at tile-boundary __syncthreads.
// Swizzle: verified formula (granule g of row r at slot g^(r&7)).
// ---------------------------------------------------------------------------
__global__ __launch_bounds__(512, 1)
void gemm8p(const __hip_bfloat16* __restrict__ A,
            const __hip_bfloat16* __restrict__ Bm,
            __hip_bfloat16* __restrict__ P,
            const int M, const int N, const int kchunk, const int S)
{
    __shared__ __hip_bfloat16 As[2][256 * 64];   // 2 x 32 KB
    __shared__ __hip_bfloat16 Bs[2][256 * 64];   // 2 x 32 KB  (total 128 KB)

    const int tid  = threadIdx.x;
    const int bn   = blockIdx.x, bm = blockIdx.y, kz = blockIdx.z;
    const int lane = tid & 63;
    const int wave = tid >> 6;          // 0..7
    const int wm   = wave >> 2;         // 0..1  (M half: 128 rows)
    const int wn   = wave & 3;          // 0..3  (N quarter: 64 cols)
    const int lm   = lane & 15, lq = lane >> 4;

    const int K  = kchunk * S;
    const int k0 = kz * kchunk;
    const int nt = kchunk >> 6;         // K-tiles of 64

    const int rlo  = lane >> 3;
    const int gsw8 = (((lane & 7) ^ rlo) << 3);

    const __hip_bfloat16* Ag = A  + (size_t)(bm * 256) * K;
    const __hip_bfloat16* Bg = Bm + (size_t)(bn * 256) * K;

    f32x4 acc[8][4];
    #pragma unroll
    for (int i = 0; i < 8; ++i)
        #pragma unroll
        for (int j = 0; j < 4; ++j)
            acc[i][j] = (f32x4){0.f, 0.f, 0.f, 0.f};

    // Wave stages chunks 4w..4w+3 of each operand (32 chunks = 256 rows each).
    auto stageA = [&](int d, int kt) {
        #pragma unroll
        for (int c = 0; c < 4; ++c) {
            const int chunk = wave * 4 + c;          // 0..31
            const int row   = chunk * 8 + rlo;       // 0..255
            gload_lds16(Ag + (size_t)row * K + kt + gsw8, &As[d][chunk * 512]);
        }
    };
    auto stageB = [&](int d, int kt) {
        #pragma unroll
        for (int c = 0; c < 4; ++c) {
            const int chunk = wave * 4 + c;
            const int row   = chunk * 8 + rlo;
            gload_lds16(Bg + (size_t)row * K + kt + gsw8, &Bs[d][chunk * 512]);
        }
    };

    // One phase: 8 ds_read_b128 + 16 MFMA, all indices compile-time.
#define PHASE(KK_, IH_, D_)                                                        \
    {                                                                              \
        const int sl = ((((KK_) * 4 + lq) ^ (lm & 7)) << 3);                       \
        bf16x8 af[4], bq[4];                                                       \
        _Pragma("unroll")                                                          \
        for (int i2 = 0; i2 < 4; ++i2)                                             \
            af[i2] = *(const bf16x8*)(&As[D_][(wm * 128 + ((IH_) * 4 + i2) * 16 + lm) * 64 + sl]); \
        _Pragma("unroll")                                                          \
        for (int j = 0; j < 4; ++j)                                                \
            bq[j] = *(const bf16x8*)(&Bs[D_][(wn * 64 + j * 16 + lm) * 64 + sl]);  \
        __builtin_amdgcn_s_setprio(1);                                             \
        _Pragma("unroll")                                                          \
        for (int i2 = 0; i2 < 4; ++i2)                                             \
            _Pragma("unroll")                                                      \
            for (int j = 0; j < 4; ++j)                                            \
                acc[(IH_) * 4 + i2][j] =                                           \
                    __builtin_amdgcn_mfma_f32_16x16x32_bf16(af[i2], bq[j],         \
                                                            acc[(IH_) * 4 + i2][j], 0, 0, 0); \
        __builtin_amdgcn_s_setprio(0);                                             \
    }

    // Prologue: stage tile 0, full drain.
    stageA(0, k0);
    stageB(0, k0);
    __syncthreads();

    int cur = 0;
    for (int t = 0; t < nt; ++t) {
        const int ktn  = k0 + (t + 1) * 64;
        const bool pre = (t + 1 < nt);
        if (cur == 0) {
            if (pre) stageA(1, ktn);           // phase 0: prefetch A(t+1)
            PHASE(0, 0, 0)
            __builtin_amdgcn_s_barrier();
            if (pre) stageB(1, ktn);           // phase 1: prefetch B(t+1)
            PHASE(0, 1, 0)
            __builtin_amdgcn_s_barrier();
            PHASE(1, 0, 0)                     // phase 2
            __builtin_amdgcn_s_barrier();
            PHASE(1, 1, 0)                     // phase 3
        } else {
            if (pre) stageA(0, ktn);
            PHASE(0, 0, 1)
            __builtin_amdgcn_s_barrier();
            if (pre) stageB(0, ktn);
            PHASE(0, 1, 1)
            __builtin_amdgcn_s_barrier();
            PHASE(1, 0, 1)
            __builtin_amdgcn_s_barrier();
            PHASE(1, 1, 1)
        }
        __syncthreads();   // tile boundary: drains vmcnt (t+1 buffer complete)
        cur ^= 1;
    }
#undef PHASE

    __hip_bfloat16* Pz = P + (size_t)kz * M * N;
    const int row0 = bm * 256 + wm * 128;
    const int colb = bn * 256 + wn * 64 + lm;
    #pragma unroll
    for (int j = 0; j < 4; ++j) {
        const int col = colb + j * 16;
        #pragma unroll
        for (int i = 0; i < 8; ++i)
            #pragma unroll
            for (int r = 0; r < 4; ++r) {
                const int row = row0 + i * 16 + lq * 4 + r;
                Pz[(size_t)row * N + col] = __float2bfloat16(acc[i][j][r]);
            }
    }
}

// T-collapse: za = sum_{u=1..T} w_u * relu(c_u*y + b2).
template <int TT>
__device__ __forceinline__ void tcollapse_coef(float be1, float be2, float be3,
                                               float* __restrict__ c, float* __restrict__ w) {
    float g[TT + 1];
    g[TT] = 1.f;
    float p3 = 1.f;
    #pragma unroll
    for (int u = TT - 1; u >= 1; --u) {
        p3 *= be3;
        g[u] = be2 * g[u + 1] + p3;
    }
    const float s = (1.f - be2) * (1.f - be3);
    float p1 = 1.f;
    #pragma unroll
    for (int u = 1; u <= TT; ++u) {
        p1 *= be1;
        c[u - 1] = 1.f - p1;
        w[u - 1] = s * g[u];
    }
}

// Sum S bf16 split-K partials + epilogue. 8 elems/thread. [R0]
template <int MODE>
__global__ void reduce_k(const __hip_bfloat16* __restrict__ P, const int S,
                         void* __restrict__ outv, const long MN, const int N,
                         const float* __restrict__ bias,
                         const float* __restrict__ b_taus,
                         const int* __restrict__ Tp)
{
    long i8 = (long)blockIdx.x * 256 + threadIdx.x;
    long i  = i8 * 8;
    float a[8] = {0.f, 0.f, 0.f, 0.f, 0.f, 0.f, 0.f, 0.f};
    for (int s = 0; s < S; ++s) {
        union { s16x8 p8; __hip_bfloat16 h[8]; } u;
        u.p8 = *(const s16x8*)(P + (size_t)s * MN + i);
        #pragma unroll
        for (int c = 0; c < 8; ++c) a[c] += __bfloat162float(u.h[c]);
    }
    const int col = (int)(i % N);
    float bb[8];
    #pragma unroll
    for (int c = 0; c < 8; ++c) bb[c] = bias[col + c];

    if constexpr (MODE == 0) {
        union { s16x8 p8; __hip_bfloat16 h[8]; } u;
        #pragma unroll
        for (int c = 0; c < 8; ++c)
            u.h[c] = __float2bfloat16(fmaxf(a[c] + bb[c], 0.f));
        ((s16x8*)outv)[i8] = u.p8;
    } else if constexpr (MODE == 1) {
        const int   T   = *Tp;
        const float be1 = 1.f / (1.f + expf(-b_taus[0]));
        const float be2 = 1.f / (1.f + expf(-b_taus[1]));
        const float be3 = 1.f / (1.f + expf(-b_taus[2]));
        union { s16x8 p8; __hip_bfloat16 h[8]; } u;
        if (T == 10) {
            float c10[10], w10[10];
            tcollapse_coef<10>(be1, be2, be3, c10, w10);
            #pragma unroll
            for (int c = 0; c < 8; ++c) {
                float za = 0.f;
                #pragma unroll
                for (int t = 0; t < 10; ++t)
                    za += w10[t] * fmaxf(fmaf(c10[t], a[c], bb[c]), 0.f);
                u.h[c] = __float2bfloat16(za);
            }
        } else {
            #pragma unroll
            for (int c = 0; c < 8; ++c) {
                float p1 = 1.f, s2 = 0.f, za = 0.f;
                for (int t = 0; t < T; ++t) {
                    p1 *= be1;
                    const float d2 = fmaxf(fmaf(1.f - p1, a[c], bb[c]), 0.f);
                    s2 = be2 * s2 + (1.f - be2) * d2;
                    za = be3 * za + (1.f - be3) * s2;
                }
                u.h[c] = __float2bfloat16(za);
            }
        }
        ((s16x8*)outv)[i8] = u.p8;
    } else {
        const int   T   = *Tp;
        const float be3 = 1.f / (1.f + expf(-b_taus[2]));
        float g = 0.f;
        for (int t = 0; t < T; ++t) g = be3 * g + (1.f - be3);
        f32x4 o0, o1;
        o0.x = a[0] + g * bb[0]; o0.y = a[1] + g * bb[1];
        o0.z = a[2] + g * bb[2]; o0.w = a[3] + g * bb[3];
        o1.x = a[4] + g * bb[4]; o1.y = a[5] + g * bb[5];
        o1.z = a[6] + g * bb[6]; o1.w = a[7] + g * bb[7];
        ((f32x4*)outv)[i8 * 2]     = o0;
        ((f32x4*)outv)[i8 * 2 + 1] = o1;
    }
}

extern "C" void kernel_launch(void* const* d_in, const int* in_sizes, int n_in,
                              void* d_out, int out_size, void* d_ws, size_t ws_size,
                              hipStream_t stream) {
    const float* x      = (const float*)d_in[0];
    const float* W1     = (const float*)d_in[1];
    const float* b1     = (const float*)d_in[2];
    const float* W2     = (const float*)d_in[3];
    const float* b2     = (const float*)d_in[4];
    const float* W3     = (const float*)d_in[5];
    const float* b3     = (const float*)d_in[6];
    const float* b_taus = (const float*)d_in[7];
    const int*   Tp     = (const int*)d_in[8];

    const int B = 1024, DIN = 2048, H1 = 4096, H2 = 4096, DOUT = 1024;
    const long MB = 1024 * 1024;

    // Arena (108 MB): xb 0 (4MB), W1b 4 (16MB), W2b 20 (32MB), W3b 52 (8MB),
    // D1b 60 (8MB), Sb 68 (8MB), Pb 76 (32MB shared by all split-K phases).
    char* ws = (char*)d_ws;
    __hip_bfloat16* xb  = (__hip_bfloat16*)(ws + 0);
    __hip_bfloat16* W1b = (__hip_bfloat16*)(ws + 4 * MB);
    __hip_bfloat16* W2b = (__hip_bfloat16*)(ws + 20 * MB);
    __hip_bfloat16* W3b = (__hip_bfloat16*)(ws + 52 * MB);
    __hip_bfloat16* D1b = (__hip_bfloat16*)(ws + 60 * MB);
    __hip_bfloat16* Sb  = (__hip_bfloat16*)(ws + 68 * MB);
    __hip_bfloat16* Pb  = (__hip_bfloat16*)(ws + 76 * MB);

    // castA: x + W1 (gates gemm1) [R0]
    cast_a_k<<<dim3(1280), dim3(256), 0, stream>>>(x, xb, W1, W1b);

    // Layer 1: R0-exact 128^2 GEMM, S=2, +1 cast plane (W2/W3).
    gemm_btk<1><<<dim3(H1 / 128, B / 128, 1 + 2), 256, 0, stream>>>(
        xb, W1b, Pb, B, H1, DIN / 2, 2,
        W2, W2b, (long)H2 * H1 / 8, W3, W3b, (long)DOUT * H2 / 8);
    reduce_k<0><<<dim3(2048), 256, 0, stream>>>(Pb, 2, (void*)D1b, (long)B * H1, H1, b1, nullptr, nullptr);

    // Layer 2: 256^2 8-phase pipelined GEMM. S=4 -> 256 blocks (1/CU),
    // kchunk=1024 -> 16 K-tiles.
    gemm8p<<<dim3(H2 / 256, B / 256, 4), 512, 0, stream>>>(
        D1b, W2b, Pb, B, H2, H1 / 4, 4);
    reduce_k<1><<<dim3(2048), 256, 0, stream>>>(Pb, 4, (void*)Sb, (long)B * H2, H2, b2, b_taus, Tp);

    // Layer 3: R0-exact 128^2 GEMM, S=8.
    gemm_btk<0><<<dim3(DOUT / 128, B / 128, 8), 256, 0, stream>>>(
        Sb, W3b, Pb, B, DOUT, H2 / 8, 8, nullptr, nullptr, 0, nullptr, nullptr, 0);
    reduce_k<2><<<dim3(512), 256, 0, stream>>>(Pb, 8, d_out, (long)B * DOUT, DOUT, b3, b_taus, Tp);
}

// Round 10
// 251.669 us; speedup vs baseline: 1.8124x; 1.8103x over previous
//
#include <hip/hip_runtime.h>
#include <hip/hip_bf16.h>
#include <stdint.h>

#define AS_GLOBAL __attribute__((address_space(1)))
#define AS_LDS    __attribute__((address_space(3)))

typedef __attribute__((ext_vector_type(8))) short  bf16x8;
typedef __attribute__((ext_vector_type(4))) float  f32x4;
typedef __attribute__((ext_vector_type(8))) short  s16x8;

__device__ __forceinline__ void gload_lds16(const void* g, void* l) {
    __builtin_amdgcn_global_load_lds((AS_GLOBAL const void*)g, (AS_LDS void*)l, 16, 0, 0);
}

// Cast 8 fp32 -> 8 bf16 (one 16B store), pair index p into region (s,d).
__device__ __forceinline__ void cast_pair(const float* __restrict__ s,
                                          __hip_bfloat16* __restrict__ d, long p) {
    f32x4 a = ((const f32x4*)s)[p * 2];
    f32x4 b = ((const f32x4*)s)[p * 2 + 1];
    union { s16x8 p8; __hip_bfloat16 h[8]; } u;
    u.h[0] = __float2bfloat16(a.x); u.h[1] = __float2bfloat16(a.y);
    u.h[2] = __float2bfloat16(a.z); u.h[3] = __float2bfloat16(a.w);
    u.h[4] = __float2bfloat16(b.x); u.h[5] = __float2bfloat16(b.y);
    u.h[6] = __float2bfloat16(b.z); u.h[7] = __float2bfloat16(b.w);
    ((s16x8*)d)[p] = u.p8;
}

// castA: x (262144 pairs) + W1 (1048576 pairs); 1280 blocks x 256 x 4 iters. [R0]
__global__ void cast_a_k(const float* __restrict__ x,  __hip_bfloat16* __restrict__ xb,
                         const float* __restrict__ W1, __hip_bfloat16* __restrict__ W1b) {
    const long nx = 262144, ntot = 1310720, stride = 1280 * 256;
    long t = (long)blockIdx.x * 256 + threadIdx.x;
    for (long p = t; p < ntot; p += stride) {
        if (p < nx) cast_pair(x, xb, p);
        else        cast_pair(W1, W1b, p - nx);
    }
}

// ---------------------------------------------------------------------------
// R10: 128x256-tile split-K GEMM, 512 threads / 8 waves. Session model
// (R0-R5): GEMM dispatch time ~ LDS-staged bytes / ~9.7 TB/s aggregate,
// insensitive to dbuf (R1), occupancy (R3), staging dtype (R2/R5). A 128x256
// tile stages A(16KB)+B(32KB)=48KB per k-step for 2x the output of a 128^2
// tile -> 25% fewer staged bytes per FLOP, while keeping the R0-verified
// per-thread acc footprint (4x4 f32x4 = 64 VGPR -- avoids R6's 256^2 VGPR
// wall), sync structure (one stage + one barrier pair per k-step), DMA path,
// and XOR swizzle (granule g of row r at slot g^(r&7); all reads preserve
// row&7 == lm&7). Wave map: wm=wave>>2 (2 x 64 rows), wn=wave&3 (4 x 64 cols).
// Staging: wave stages A-chunks {2w,2w+1} and B-chunks {4w..4w+3} (1KB each).
// LDS 48KB -> 2-3 blocks/CU. FUSECAST leading z-planes cast W2/W3 (128 blocks
// per plane at 512 thr; CP=2 -> same 131072 cast threads as R0).
// ---------------------------------------------------------------------------
template <int FUSECAST>
__global__ __launch_bounds__(512, 2)
void gemm_w(const __hip_bfloat16* __restrict__ A,
            const __hip_bfloat16* __restrict__ Bm,
            __hip_bfloat16* __restrict__ P,
            const int M, const int N, const int kchunk, const int S,
            const float* __restrict__ cs1, __hip_bfloat16* __restrict__ cd1, const long cn1,
            const float* __restrict__ cs2, __hip_bfloat16* __restrict__ cd2, const long cn2)
{
    __shared__ __hip_bfloat16 As[128 * 64];   // 16 KB
    __shared__ __hip_bfloat16 Bs[256 * 64];   // 32 KB

    const int tid = threadIdx.x;
    const int bn = blockIdx.x, bm = blockIdx.y, z = blockIdx.z;

    if (FUSECAST && z < FUSECAST) {
        const long nb     = (long)gridDim.x * gridDim.y;
        const long stride = FUSECAST * nb * 512;
        long t = ((long)z * nb + (long)bm * gridDim.x + bn) * 512 + tid;
        const long ntot = cn1 + cn2;
        for (long p = t; p < ntot; p += stride) {
            if (p < cn1) cast_pair(cs1, cd1, p);
            else         cast_pair(cs2, cd2, p - cn1);
        }
        return;
    }
    const int kz = z - FUSECAST;

    const int lane = tid & 63;
    const int wave = tid >> 6;          // 0..7
    const int wm   = wave >> 2;         // 0..1 : 64-row band within 128
    const int wn   = wave & 3;          // 0..3 : 64-col band within 256
    const int lm   = lane & 15, lq = lane >> 4;

    const int K  = kchunk * S;
    const int k0 = kz * kchunk;

    const int rlo  = lane >> 3;                  // row within an 8-row chunk
    const int gsw8 = (((lane & 7) ^ rlo) << 3);  // swizzled granule offset

    const __hip_bfloat16* Ag = A  + (size_t)(bm * 128) * K;
    const __hip_bfloat16* Bg = Bm + (size_t)(bn * 256) * K;

    f32x4 acc[4][4];
    #pragma unroll
    for (int i = 0; i < 4; ++i)
        #pragma unroll
        for (int j = 0; j < 4; ++j)
            acc[i][j] = (f32x4){0.f, 0.f, 0.f, 0.f};

    for (int kt = k0; kt < k0 + kchunk; kt += 64) {
        __syncthreads();
        // A: 16 chunks (128 rows), wave stages 2.
        #pragma unroll
        for (int c = 0; c < 2; ++c) {
            const int chunk = wave * 2 + c;      // 0..15
            const int row   = chunk * 8 + rlo;   // 0..127
            gload_lds16(Ag + (size_t)row * K + kt + gsw8, As + chunk * 512);
        }
        // B: 32 chunks (256 rows), wave stages 4.
        #pragma unroll
        for (int c = 0; c < 4; ++c) {
            const int chunk = wave * 4 + c;      // 0..31
            const int row   = chunk * 8 + rlo;   // 0..255
            gload_lds16(Bg + (size_t)row * K + kt + gsw8, Bs + chunk * 512);
        }
        __syncthreads();
        #pragma unroll
        for (int kk = 0; kk < 2; ++kk) {
            // granule G = kk*4+lq of row lives at slot G^(row&7); row&7 == lm&7
            const int sl = (((kk * 4 + lq) ^ (lm & 7)) << 3);
            bf16x8 af[4], bq[4];
            #pragma unroll
            for (int i = 0; i < 4; ++i)
                af[i] = *(const bf16x8*)(As + (wm * 64 + i * 16 + lm) * 64 + sl);
            #pragma unroll
            for (int j = 0; j < 4; ++j)
                bq[j] = *(const bf16x8*)(Bs + (wn * 64 + j * 16 + lm) * 64 + sl);
            #pragma unroll
            for (int i = 0; i < 4; ++i)
                #pragma unroll
                for (int j = 0; j < 4; ++j)
                    acc[i][j] = __builtin_amdgcn_mfma_f32_16x16x32_bf16(af[i], bq[j], acc[i][j], 0, 0, 0);
        }
    }

    __hip_bfloat16* Pz = P + (size_t)kz * M * N;
    const int row0 = bm * 128 + wm * 64;
    const int colb = bn * 256 + wn * 64 + lm;
    #pragma unroll
    for (int j = 0; j < 4; ++j) {
        const int col = colb + j * 16;
        #pragma unroll
        for (int i = 0; i < 4; ++i)
            #pragma unroll
            for (int r = 0; r < 4; ++r) {
                const int row = row0 + i * 16 + lq * 4 + r;
                Pz[(size_t)row * N + col] = __float2bfloat16(acc[i][j][r]);
            }
    }
}

// T-collapse: za = sum_{u=1..T} w_u * relu(c_u*y + b2).
template <int TT>
__device__ __forceinline__ void tcollapse_coef(float be1, float be2, float be3,
                                               float* __restrict__ c, float* __restrict__ w) {
    float g[TT + 1];
    g[TT] = 1.f;
    float p3 = 1.f;
    #pragma unroll
    for (int u = TT - 1; u >= 1; --u) {
        p3 *= be3;
        g[u] = be2 * g[u + 1] + p3;
    }
    const float s = (1.f - be2) * (1.f - be3);
    float p1 = 1.f;
    #pragma unroll
    for (int u = 1; u <= TT; ++u) {
        p1 *= be1;
        c[u - 1] = 1.f - p1;
        w[u - 1] = s * g[u];
    }
}

// Sum S bf16 split-K partials + epilogue. 8 elems/thread. [R0]
// MODE 0: bf16 out = relu(sum + bias); MODE 1: T-collapse; MODE 2: f32 out.
template <int MODE>
__global__ void reduce_k(const __hip_bfloat16* __restrict__ P, const int S,
                         void* __restrict__ outv, const long MN, const int N,
                         const float* __restrict__ bias,
                         const float* __restrict__ b_taus,
                         const int* __restrict__ Tp)
{
    long i8 = (long)blockIdx.x * 256 + threadIdx.x;
    long i  = i8 * 8;
    float a[8] = {0.f, 0.f, 0.f, 0.f, 0.f, 0.f, 0.f, 0.f};
    for (int s = 0; s < S; ++s) {
        union { s16x8 p8; __hip_bfloat16 h[8]; } u;
        u.p8 = *(const s16x8*)(P + (size_t)s * MN + i);
        #pragma unroll
        for (int c = 0; c < 8; ++c) a[c] += __bfloat162float(u.h[c]);
    }
    const int col = (int)(i % N);
    float bb[8];
    #pragma unroll
    for (int c = 0; c < 8; ++c) bb[c] = bias[col + c];

    if constexpr (MODE == 0) {
        union { s16x8 p8; __hip_bfloat16 h[8]; } u;
        #pragma unroll
        for (int c = 0; c < 8; ++c)
            u.h[c] = __float2bfloat16(fmaxf(a[c] + bb[c], 0.f));
        ((s16x8*)outv)[i8] = u.p8;
    } else if constexpr (MODE == 1) {
        const int   T   = *Tp;
        const float be1 = 1.f / (1.f + expf(-b_taus[0]));
        const float be2 = 1.f / (1.f + expf(-b_taus[1]));
        const float be3 = 1.f / (1.f + expf(-b_taus[2]));
        union { s16x8 p8; __hip_bfloat16 h[8]; } u;
        if (T == 10) {
            float c10[10], w10[10];
            tcollapse_coef<10>(be1, be2, be3, c10, w10);
            #pragma unroll
            for (int c = 0; c < 8; ++c) {
                float za = 0.f;
                #pragma unroll
                for (int t = 0; t < 10; ++t)
                    za += w10[t] * fmaxf(fmaf(c10[t], a[c], bb[c]), 0.f);
                u.h[c] = __float2bfloat16(za);
            }
        } else {
            #pragma unroll
            for (int c = 0; c < 8; ++c) {
                float p1 = 1.f, s2 = 0.f, za = 0.f;
                for (int t = 0; t < T; ++t) {
                    p1 *= be1;
                    const float d2 = fmaxf(fmaf(1.f - p1, a[c], bb[c]), 0.f);
                    s2 = be2 * s2 + (1.f - be2) * d2;
                    za = be3 * za + (1.f - be3) * s2;
                }
                u.h[c] = __float2bfloat16(za);
            }
        }
        ((s16x8*)outv)[i8] = u.p8;
    } else {
        const int   T   = *Tp;
        const float be3 = 1.f / (1.f + expf(-b_taus[2]));
        float g = 0.f;
        for (int t = 0; t < T; ++t) g = be3 * g + (1.f - be3);   // 1 - beta3^T
        f32x4 o0, o1;
        o0.x = a[0] + g * bb[0]; o0.y = a[1] + g * bb[1];
        o0.z = a[2] + g * bb[2]; o0.w = a[3] + g * bb[3];
        o1.x = a[4] + g * bb[4]; o1.y = a[5] + g * bb[5];
        o1.z = a[6] + g * bb[6]; o1.w = a[7] + g * bb[7];
        ((f32x4*)outv)[i8 * 2]     = o0;
        ((f32x4*)outv)[i8 * 2 + 1] = o1;
    }
}

extern "C" void kernel_launch(void* const* d_in, const int* in_sizes, int n_in,
                              void* d_out, int out_size, void* d_ws, size_t ws_size,
                              hipStream_t stream) {
    const float* x      = (const float*)d_in[0];
    const float* W1     = (const float*)d_in[1];
    const float* b1     = (const float*)d_in[2];
    const float* W2     = (const float*)d_in[3];
    const float* b2     = (const float*)d_in[4];
    const float* W3     = (const float*)d_in[5];
    const float* b3     = (const float*)d_in[6];
    const float* b_taus = (const float*)d_in[7];
    const int*   Tp     = (const int*)d_in[8];

    const int B = 1024, DIN = 2048, H1 = 4096, H2 = 4096, DOUT = 1024;
    const long MB = 1024 * 1024;

    // Arena (108 MB): xb 0 (4MB), W1b 4 (16MB), W2b 20 (32MB), W3b 52 (8MB),
    // D1b 60 (8MB), Sb 68 (8MB), Pb 76 (32MB shared by all split-K phases).
    char* ws = (char*)d_ws;
    __hip_bfloat16* xb  = (__hip_bfloat16*)(ws + 0);
    __hip_bfloat16* W1b = (__hip_bfloat16*)(ws + 4 * MB);
    __hip_bfloat16* W2b = (__hip_bfloat16*)(ws + 20 * MB);
    __hip_bfloat16* W3b = (__hip_bfloat16*)(ws + 52 * MB);
    __hip_bfloat16* D1b = (__hip_bfloat16*)(ws + 60 * MB);
    __hip_bfloat16* Sb  = (__hip_bfloat16*)(ws + 68 * MB);
    __hip_bfloat16* Pb  = (__hip_bfloat16*)(ws + 76 * MB);

    // castA: x + W1 (gates gemm1) [R0]
    cast_a_k<<<dim3(1280), dim3(256), 0, stream>>>(x, xb, W1, W1b);

    // Layer 1: 128x256 GEMM, S=2 (256 GEMM blocks) + 2 cast planes
    // (2 x 128 blocks x 512 thr = same 131072 cast threads as R0).
    // 512 total blocks at 2/CU: each CU ~1 GEMM + ~1 cast (the R0 mix).
    gemm_w<2><<<dim3(H1 / 256, B / 128, 2 + 2), 512, 0, stream>>>(
        xb, W1b, Pb, B, H1, DIN / 2, 2,
        W2, W2b, (long)H2 * H1 / 8, W3, W3b, (long)DOUT * H2 / 8);
    reduce_k<0><<<dim3(2048), 256, 0, stream>>>(Pb, 2, (void*)D1b, (long)B * H1, H1, b1, nullptr, nullptr);

    // Layer 2: S=4 -> (16,8,4) = 512 blocks (one 2/CU residency round).
    gemm_w<0><<<dim3(H2 / 256, B / 128, 4), 512, 0, stream>>>(
        D1b, W2b, Pb, B, H2, H1 / 4, 4,
        nullptr, nullptr, 0, nullptr, nullptr, 0);
    reduce_k<1><<<dim3(2048), 256, 0, stream>>>(Pb, 4, (void*)Sb, (long)B * H2, H2, b2, b_taus, Tp);

    // Layer 3: S=8 -> (4,8,8) = 256 blocks.
    gemm_w<0><<<dim3(DOUT / 256, B / 128, 8), 512, 0, stream>>>(
        Sb, W3b, Pb, B, DOUT, H2 / 8, 8,
        nullptr, nullptr, 0, nullptr, nullptr, 0);
    reduce_k<2><<<dim3(512), 256, 0, stream>>>(Pb, 8, d_out, (long)B * DOUT, DOUT, b3, b_taus, Tp);
}